// Round 19
// baseline (39.334 us; speedup 1.0000x reference)
//
#include <hip/hip_runtime.h>
#include <hip/hip_bf16.h>

#define OUT_N 8192
#define IN_N  8192
#define QROW  (IN_N / 2)     // 4096 int32 per out row (one widened byte each)
#define CH32  64             // int32 per row per sub-chunk (256-B granule)

typedef __attribute__((ext_vector_type(8))) short short8v;  // 8 bf16
typedef __attribute__((ext_vector_type(4))) float f32x4;

__device__ __forceinline__ unsigned int bf16pk(float a, float b) {
    __hip_bfloat162 h = __float22bfloat162_rn(make_float2(a, b));
    unsigned int u;
    __builtin_memcpy(&u, &h, 4);
    return u;
}

#define SCHED0() __builtin_amdgcn_sched_barrier(0)
#define WAITV(n) asm volatile("s_waitcnt vmcnt(" #n ")" ::: "memory")
#define WAITL()  asm volatile("s_waitcnt lgkmcnt(0)" ::: "memory")

// Single fused kernel: R18's proven hand-unrolled reg-staged engine + direct
// fp32 x loads with in-register bf16 conversion (xconv pre-pass eliminated).
// One block = one 16-out-row tile; 8 waves split K 8 ways; wave-private LDS
// q double buffer; NO block barrier in the main loop; counted vmcnt ledger
// never drops below 4 outstanding:
//   body: WAITL -> COMPUTE(c) -> WAITV(8)[q(c+1)] -> QST -> QLD(c+2)
//         -> WAITV(4)[xf(c+1)] -> CONVERT -> XFLD(c+2)
// Chunk addresses rotated by ph = tile & 7 (K-order free).
// LDS swizzle: slot j of row R stored at j^R (load addr pre-swizzled).
__global__ __launch_bounds__(512, 4) void qlin_mfma_kernel(
    const int*   __restrict__ qp,
    const float* __restrict__ x,
    const float* __restrict__ scale,
    const float* __restrict__ bias,
    float*       __restrict__ out)
{
    __shared__ int   qbuf[8][2][16 * CH32];   // 8 waves x 2 x 4KB = 64 KB
    __shared__ float red[8][16][17];          // 8.7 KB reduction scratch

    const int t = threadIdx.x;
    const int w = t >> 6;
    const int l = t & 63;
    const int g = l >> 4;
    const int r = l & 15;
    const int tile = blockIdx.x;
    const int obase = tile * 16;
    const int ph = tile & 7;

    const int* qwbase = qp + (size_t)obase * QROW + w * (QROW / 8);
    const int drow = l >> 4;
    // x fp32 fragment base: elem = r*IN_N + w*1024 + cc*128 + s*32 + g*8
    const float* xwbase = x + (size_t)r * IN_N + w * (IN_N / 8) + g * 8;

    f32x4 acc = {0.f, 0.f, 0.f, 0.f};
    int4   qr0, qr1, qr2, qr3;                   // q staging (16 VGPR)
    float4 xf0, xf1, xf2, xf3, xf4, xf5, xf6, xf7; // fp32 x staging (32 VGPR)
    uint4  xc0, xc1, xc2, xc3;                   // converted bf16 x (16 VGPR)

#define QLD(c_) do {                                                          \
    const int cc = ((c_) + ph) & 7;                                           \
    const int r0 = 0 + drow, r1 = 4 + drow, r2 = 8 + drow, r3 = 12 + drow;    \
    qr0 = *(const int4*)(qwbase + (size_t)r0 * QROW + cc * CH32 + (((l & 15) ^ r0) << 2)); \
    qr1 = *(const int4*)(qwbase + (size_t)r1 * QROW + cc * CH32 + (((l & 15) ^ r1) << 2)); \
    qr2 = *(const int4*)(qwbase + (size_t)r2 * QROW + cc * CH32 + (((l & 15) ^ r2) << 2)); \
    qr3 = *(const int4*)(qwbase + (size_t)r3 * QROW + cc * CH32 + (((l & 15) ^ r3) << 2)); \
    } while (0)

#define XFLD(c_) do {                                                         \
    const int cc = ((c_) + ph) & 7;                                           \
    const float* xp = xwbase + cc * 128;                                      \
    xf0 = *(const float4*)(xp +   0); xf1 = *(const float4*)(xp +   4);       \
    xf2 = *(const float4*)(xp +  32); xf3 = *(const float4*)(xp +  36);       \
    xf4 = *(const float4*)(xp +  64); xf5 = *(const float4*)(xp +  68);       \
    xf6 = *(const float4*)(xp +  96); xf7 = *(const float4*)(xp + 100);       \
    } while (0)

#define CONVERT() do {                                                        \
    xc0 = (uint4){ bf16pk(xf0.x, xf0.y), bf16pk(xf0.z, xf0.w),                \
                   bf16pk(xf1.x, xf1.y), bf16pk(xf1.z, xf1.w) };              \
    xc1 = (uint4){ bf16pk(xf2.x, xf2.y), bf16pk(xf2.z, xf2.w),                \
                   bf16pk(xf3.x, xf3.y), bf16pk(xf3.z, xf3.w) };              \
    xc2 = (uint4){ bf16pk(xf4.x, xf4.y), bf16pk(xf4.z, xf4.w),                \
                   bf16pk(xf5.x, xf5.y), bf16pk(xf5.z, xf5.w) };              \
    xc3 = (uint4){ bf16pk(xf6.x, xf6.y), bf16pk(xf6.z, xf6.w),                \
                   bf16pk(xf7.x, xf7.y), bf16pk(xf7.z, xf7.w) };              \
    } while (0)

#define QST(PAR) do {                                                         \
    *(int4*)&qbuf[w][PAR][0 * 256 + l * 4] = qr0;                             \
    *(int4*)&qbuf[w][PAR][1 * 256 + l * 4] = qr1;                             \
    *(int4*)&qbuf[w][PAR][2 * 256 + l * 4] = qr2;                             \
    *(int4*)&qbuf[w][PAR][3 * 256 + l * 4] = qr3;                             \
    } while (0)

#define STEP(PAR, S, XV) do {                                                 \
    const int4 q = *(const int4*)((const char*)qbuf[w][PAR] + r * 256         \
                                  + (((((S) << 2) + g) ^ r) << 4));           \
    uint4 ub = {                                                              \
        bf16pk((float)((q.x << 28) >> 28), (float)((q.x << 24) >> 28)),       \
        bf16pk((float)((q.y << 28) >> 28), (float)((q.y << 24) >> 28)),       \
        bf16pk((float)((q.z << 28) >> 28), (float)((q.z << 24) >> 28)),       \
        bf16pk((float)((q.w << 28) >> 28), (float)((q.w << 24) >> 28))        \
    };                                                                        \
    short8v bfrag = __builtin_bit_cast(short8v, ub);                          \
    short8v afrag = __builtin_bit_cast(short8v, XV);                          \
    acc = __builtin_amdgcn_mfma_f32_16x16x32_bf16(afrag, bfrag, acc, 0, 0, 0);\
    } while (0)

#define COMPUTE(PAR) do {                                                     \
    STEP(PAR, 0, xc0); STEP(PAR, 1, xc1); STEP(PAR, 2, xc2); STEP(PAR, 3, xc3); \
    } while (0)

    // BODY entry invariant: LDS[PAR]=q(c); xc=x(c); outstanding q(c+1)[4]
    // then xf(c+1)[8] = 12
#define BODY(PAR, NPAR, Cp2) do {                                             \
        WAITL(); SCHED0();                                                    \
        COMPUTE(PAR);                                                         \
        SCHED0(); WAITV(8); SCHED0();      /* q(c+1) arrived */               \
        QST(NPAR);                                                            \
        QLD(Cp2);                          /* out: xf8 + q4 = 12 */           \
        SCHED0(); WAITV(4); SCHED0();      /* xf(c+1) arrived */              \
        CONVERT();                         /* xc = x(c+1) */                  \
        XFLD(Cp2);                         /* out: q4 + xf8 = 12 */           \
    } while (0)

    // ---- prologue
    QLD(0); XFLD(0);                       // out: q(0)4 + xf(0)8 = 12
    WAITV(8); SCHED0();                    // q(0) arrived
    QST(0);
    QLD(1);                                // out: xf(0)8 + q(1)4 = 12
    WAITV(4); SCHED0();                    // xf(0) arrived
    CONVERT();                             // xc = x(0)
    XFLD(1);                               // out: q(1)4 + xf(1)8 = 12

    BODY(0, 1, 2);
    BODY(1, 0, 3);
    BODY(0, 1, 4);
    BODY(1, 0, 5);
    BODY(0, 1, 6);
    BODY(1, 0, 7);
    // c=6: no c+2 issue
    WAITL(); SCHED0();
    COMPUTE(0);
    SCHED0(); WAITV(8); SCHED0();          // q(7) arrived
    QST(1);
    WAITV(0); SCHED0();                    // xf(7) arrived
    CONVERT();
    // c=7
    WAITL(); SCHED0();
    COMPUTE(1);

#undef QLD
#undef XFLD
#undef CONVERT
#undef QST
#undef STEP
#undef COMPUTE
#undef BODY

    // ---- cross-wave K reduction; D map: col=lane&15 (out), row=(lane>>4)*4+j
    red[w][g * 4 + 0][r] = acc[0];
    red[w][g * 4 + 1][r] = acc[1];
    red[w][g * 4 + 2][r] = acc[2];
    red[w][g * 4 + 3][r] = acc[3];
    __syncthreads();

    if (t < 256) {
        const int b = t >> 4;
        const int o = t & 15;
        const int oc = obase + o;
        float v = 0.f;
        #pragma unroll
        for (int i = 0; i < 8; ++i) v += red[i][b][o];
        out[b * OUT_N + oc] = v * scale[oc >> 7] + bias[oc];
    }
}

extern "C" void kernel_launch(void* const* d_in, const int* in_sizes, int n_in,
                              void* d_out, int out_size, void* d_ws, size_t ws_size,
                              hipStream_t stream) {
    (void)in_sizes; (void)n_in; (void)d_ws; (void)ws_size; (void)out_size;
    const float* x     = (const float*)d_in[0];
    const int*   qp    = (const int*)d_in[1];
    const float* scale = (const float*)d_in[2];
    const float* bias  = (const float*)d_in[3];
    float*       out   = (float*)d_out;

    qlin_mfma_kernel<<<dim3(OUT_N / 16), dim3(512), 0, stream>>>(qp, x, scale, bias, out);
}